// Round 4
// baseline (264.397 us; speedup 1.0000x reference)
//
#include <hip/hip_runtime.h>

// RWKV-7 DPLR single-step decode: B=64, H=32, K=V=128, fp32.
// v5: two-pass split. Rounds 1-3 evidence: four structurally different
// fused kernels all pinned at 82-87us / 2.5 TB/s, while the trivial
// barrier-free fillBuffer kernel hits 6.5 TB/s (528MB/83us) at 9.7%
// occupancy on the same chip. Conclusion: the per-iteration
// reduce->barrier->consume coupling gates wave memory issue; pipelining
// around it inside a block failed 4x. So: remove the coupling.
//   Kernel A: read H once, reduce s/t/alpha/beta, write o + s(ws).
//   Kernel B: Ht = g*H + b s^T + k v^T  -- pure stream, 1 barrier,
//             then 16 independent load->fma->nt-store chains/thread.
// B's h0 re-read should hit L3 (134MB < 256MB, just written by A).

#define KD 128
#define VD 128
#define BH_TOTAL 2048   // B*H = 64*32

typedef float f32x4 __attribute__((ext_vector_type(4)));

// ---------------- Kernel A: reduce + o-write -------------------------
__global__ __launch_bounds__(256) void dplr_reduce_kernel(
    const float* __restrict__ q_,  const float* __restrict__ k_,
    const float* __restrict__ v_,  const float* __restrict__ a_,
    const float* __restrict__ b_,  const float* __restrict__ gk_,
    const float* __restrict__ h0_, float* __restrict__ out_,
    float* __restrict__ s_ws)
{
    const int bh  = blockIdx.x;
    const int tid = threadIdx.x;         // 0..255
    const int c4  = (tid & 31) * 4;
    const int grp = tid >> 5;            // 0..7
    const int r0  = grp * 16;
    const size_t vec_off = (size_t)bh * KD;

    __shared__ float qs[KD], ks[KD], bs[KD], as_[KD], qgs[KD];
    __shared__ float sred[8][VD], tred[8][VD];
    __shared__ float red2[2];            // [0]=alpha, [1]=beta

    float vv = 0.f;
    if (tid < KD) {
        const float qq = q_[vec_off + tid];
        const float gg = expf(gk_[vec_off + tid]);
        qs[tid]  = qq;
        ks[tid]  = k_[vec_off + tid];
        bs[tid]  = b_[vec_off + tid];
        as_[tid] = a_[vec_off + tid];
        qgs[tid] = qq * gg;
        vv       = v_[vec_off + tid];
    }
    __syncthreads();

    // alpha = q.b (wave 0), beta = q.k (wave 1)
    if (tid < 64) {
        float p = qs[tid] * bs[tid] + qs[tid + 64] * bs[tid + 64];
#pragma unroll
        for (int o = 32; o > 0; o >>= 1) p += __shfl_down(p, o, 64);
        if (tid == 0) red2[0] = p;
    } else if (tid < 128) {
        const int l = tid - 64;
        float p = qs[l] * ks[l] + qs[l + 64] * ks[l + 64];
#pragma unroll
        for (int o = 32; o > 0; o >>= 1) p += __shfl_down(p, o, 64);
        if (l == 0) red2[1] = p;
    }

    // partial s/t over my 16 rows (load -> fma -> discard; no residency)
    f32x4 sp = {0.f, 0.f, 0.f, 0.f};
    f32x4 tp = {0.f, 0.f, 0.f, 0.f};
    const float* hp = h0_ + (size_t)bh * (KD * VD) + (size_t)r0 * VD + c4;
#pragma unroll
    for (int j = 0; j < 16; ++j) {
        const f32x4 h = *(const f32x4*)(hp + (size_t)j * VD);
        sp += as_[r0 + j] * h;
        tp += qgs[r0 + j] * h;
    }
    *(f32x4*)&sred[grp][c4] = sp;
    *(f32x4*)&tred[grp][c4] = tp;
    __syncthreads();

    if (tid < VD) {
        float sc = 0.f, tc = 0.f;
#pragma unroll
        for (int g = 0; g < 8; ++g) { sc += sred[g][tid]; tc += tred[g][tid]; }
        out_[(size_t)bh * VD + tid] = tc + red2[0] * sc + red2[1] * vv;
        s_ws[(size_t)bh * VD + tid] = sc;
    }
}

// ---------------- Kernel B: Ht update (pure stream) ------------------
__global__ __launch_bounds__(256) void dplr_update_kernel(
    const float* __restrict__ k_,  const float* __restrict__ v_,
    const float* __restrict__ b_,  const float* __restrict__ gk_,
    const float* __restrict__ h0_, const float* __restrict__ s_ws,
    float* __restrict__ out_)
{
    const int bh  = blockIdx.x;
    const int tid = threadIdx.x;         // 0..255
    const int c4  = (tid & 31) * 4;
    const int grp = tid >> 5;            // 0..7
    const int r0  = grp * 16;
    const size_t vec_off = (size_t)bh * KD;

    __shared__ float ks[KD], bs[KD], gs[KD], vs[KD], ss[KD];

    if (tid < KD) {
        ks[tid] = k_[vec_off + tid];
        bs[tid] = b_[vec_off + tid];
        gs[tid] = expf(gk_[vec_off + tid]);
        vs[tid] = v_[vec_off + tid];
        ss[tid] = s_ws[vec_off + tid];
    }
    __syncthreads();

    const f32x4 s4 = *(const f32x4*)&ss[c4];
    const f32x4 v4 = *(const f32x4*)&vs[c4];
    const float* hp = h0_ + (size_t)bh * (KD * VD) + (size_t)r0 * VD + c4;
    float* op = out_ + (size_t)BH_TOTAL * VD
              + (size_t)bh * (KD * VD) + (size_t)r0 * VD + c4;

    // 16 independent load->fma->store chains; no barriers, no coupling.
#pragma unroll
    for (int j = 0; j < 16; ++j) {
        const int r = r0 + j;
        const f32x4 h = *(const f32x4*)(hp + (size_t)j * VD);
        f32x4 o4 = gs[r] * h + bs[r] * s4 + ks[r] * v4;
        __builtin_nontemporal_store(o4, (f32x4*)(op + (size_t)j * VD));
    }
}

// ---------------- Fallback: fused v3 (known-passing) -----------------
__global__ __launch_bounds__(512, 4) void dplr_fused_kernel(
    const float* __restrict__ q_,  const float* __restrict__ k_,
    const float* __restrict__ v_,  const float* __restrict__ a_,
    const float* __restrict__ b_,  const float* __restrict__ gk_,
    const float* __restrict__ h0_, float* __restrict__ out_)
{
    const int bh  = blockIdx.x;
    const int tid = threadIdx.x;
    const int c4  = (tid & 31) * 4;
    const int grp = tid >> 5;
    const int r0  = grp * 8;

    const size_t vec_off = (size_t)bh * KD;
    const size_t h_off   = (size_t)bh * (KD * VD);

    __shared__ float qs[KD], ks[KD], bs[KD], as_[KD], gs[KD], qgs[KD], vs[KD];
    __shared__ float sred[16][VD];
    __shared__ float tred[16][VD];
    __shared__ float red2[2];

    f32x4 Hreg[8];
    const float* hp = h0_ + h_off + (size_t)r0 * VD + c4;
#pragma unroll
    for (int j = 0; j < 8; ++j) Hreg[j] = *(const f32x4*)(hp + (size_t)j * VD);

    const f32x4 v4 = *(const f32x4*)(v_ + vec_off + c4);

    if (tid < KD) {
        float qq = q_[vec_off + tid];
        float gg = expf(gk_[vec_off + tid]);
        qs[tid]  = qq;  ks[tid]  = k_[vec_off + tid];
        bs[tid]  = b_[vec_off + tid];  as_[tid] = a_[vec_off + tid];
        gs[tid]  = gg;  qgs[tid] = qq * gg;  vs[tid] = v_[vec_off + tid];
    }
#pragma unroll
    for (int j = 0; j < 8; ++j) asm volatile("" : "+v"(Hreg[j]));
    __syncthreads();

    if (tid < 64) {
        float p = qs[tid] * bs[tid] + qs[tid + 64] * bs[tid + 64];
#pragma unroll
        for (int o = 32; o > 0; o >>= 1) p += __shfl_down(p, o, 64);
        if (tid == 0) red2[0] = p;
    } else if (tid < 128) {
        int l = tid - 64;
        float p = qs[l] * ks[l] + qs[l + 64] * ks[l + 64];
#pragma unroll
        for (int o = 32; o > 0; o >>= 1) p += __shfl_down(p, o, 64);
        if (l == 0) red2[1] = p;
    }

    f32x4 sp = {0.f,0.f,0.f,0.f}, tp = {0.f,0.f,0.f,0.f};
#pragma unroll
    for (int j = 0; j < 8; ++j) {
        sp += as_[r0 + j] * Hreg[j];
        tp += qgs[r0 + j] * Hreg[j];
    }
    *(f32x4*)&sred[grp][c4] = sp;
    *(f32x4*)&tred[grp][c4] = tp;
    __syncthreads();

    f32x4 s4 = {0.f,0.f,0.f,0.f};
#pragma unroll
    for (int g = 0; g < 16; ++g) s4 += *(const f32x4*)&sred[g][c4];

    if (tid < VD) {
        float sc = 0.f, tc = 0.f;
#pragma unroll
        for (int g = 0; g < 16; ++g) { sc += sred[g][tid]; tc += tred[g][tid]; }
        out_[(size_t)bh * VD + tid] = tc + red2[0]*sc + red2[1]*vs[tid];
    }

    float* op = out_ + (size_t)BH_TOTAL * VD + h_off + (size_t)r0 * VD + c4;
#pragma unroll
    for (int j = 0; j < 8; ++j) {
        const int r = r0 + j;
        f32x4 o4 = gs[r]*Hreg[j] + bs[r]*s4 + ks[r]*v4;
        __builtin_nontemporal_store(o4, (f32x4*)(op + (size_t)j * VD));
    }
}

extern "C" void kernel_launch(void* const* d_in, const int* in_sizes, int n_in,
                              void* d_out, int out_size, void* d_ws, size_t ws_size,
                              hipStream_t stream) {
    const float* q  = (const float*)d_in[0];
    const float* k  = (const float*)d_in[1];
    const float* v  = (const float*)d_in[2];
    const float* a  = (const float*)d_in[3];
    const float* b  = (const float*)d_in[4];
    const float* gk = (const float*)d_in[5];
    const float* h0 = (const float*)d_in[6];
    float* out = (float*)d_out;

    const size_t need = (size_t)BH_TOTAL * VD * sizeof(float);
    if (d_ws != nullptr && ws_size >= need) {
        float* s_ws = (float*)d_ws;
        dplr_reduce_kernel<<<BH_TOTAL, 256, 0, stream>>>(q, k, v, a, b, gk, h0, out, s_ws);
        dplr_update_kernel<<<BH_TOTAL, 256, 0, stream>>>(k, v, b, gk, h0, s_ws, out);
    } else {
        dplr_fused_kernel<<<BH_TOTAL, 512, 0, stream>>>(q, k, v, a, b, gk, h0, out);
    }
}

// Round 5
// 254.425 us; speedup vs baseline: 1.0392x; 1.0392x over previous
//
#include <hip/hip_runtime.h>

// RWKV-7 DPLR single-step decode: B=64, H=32, K=V=128, fp32.
// v6: ONE WAVE PER (b,h), zero barriers, zero cross-wave coupling.
// Rounds 1-4 evidence: every kernel with block-wide reduce->barrier->
// consume caps at 2.4-2.5 TB/s; the harness's barrier-free fillBuffer
// hits 6.6-6.9 TB/s at 9% occupancy on the same chip. So make every
// wave fully independent:
//   - wave w owns bh=w; lanes 0-31 take even rows, 32-63 odd rows
//     -> each wave-instruction touches ONE contiguous 1KB segment.
//   - s/t reduction becomes wave-local: per-lane partials over 64 rows,
//     then a single shfl_xor(32) combine. alpha/beta: butterfly reduce.
//   - per-row scalars (a, q*g, g, b, k) broadcast from wave-private LDS
//     slices (parity-split so chunked ds_read_b128 works). No barrier
//     needed: same wave writes then reads (lgkmcnt-ordered).
//   - H read twice; 2nd read is us-later -> L3-hot; last 16 chunks kept
//     in registers (free: occupancy is grid-bound at 8 waves/CU).
// Phase-2 H loads + Ht stores are nontemporal (last use / write-only).

#define KD 128
#define VD 128
#define BH_TOTAL 2048        // B*H
#define WPB 4                // waves per block (256 threads)
#define NBLK (BH_TOTAL/WPB)  // 512 blocks = 2 per CU
#define RKEEP 16             // register-resident chunks (of 64) per lane
#define NSTRM (64 - RKEEP)   // streamed chunks (48 = 12 blocks of 4)

typedef float f32x4 __attribute__((ext_vector_type(4)));

__global__ __launch_bounds__(256, 2) void dplr_decode_wave_kernel(
    const float* __restrict__ q_,  const float* __restrict__ k_,
    const float* __restrict__ v_,  const float* __restrict__ a_,
    const float* __restrict__ b_,  const float* __restrict__ gk_,
    const float* __restrict__ h0_, float* __restrict__ out_)
{
    const int tid  = threadIdx.x;
    const int wid  = tid >> 6;           // wave in block, 0..3
    const int lane = tid & 63;
    const int bh   = blockIdx.x * WPB + wid;
    const int half = lane >> 5;          // 0: even rows, 1: odd rows
    const int c4   = (lane & 31) * 4;    // column base, 0..124

    const size_t vec_off = (size_t)bh * KD;
    const size_t h_off   = (size_t)bh * (KD * VD);

    // wave-private LDS slices, parity-split: [wid][parity][chunk]
    __shared__ float aL[WPB][2][64], qgL[WPB][2][64], gL[WPB][2][64],
                     bL[WPB][2][64], kL[WPB][2][64];

    // ---- stage per-(b,h) vectors: lane loads elements lane, lane+64 ----
    const float q_lo = q_[vec_off + lane],  q_hi = q_[vec_off + lane + 64];
    const float b_lo = b_[vec_off + lane],  b_hi = b_[vec_off + lane + 64];
    const float k_lo = k_[vec_off + lane],  k_hi = k_[vec_off + lane + 64];
    const float a_lo = a_[vec_off + lane],  a_hi = a_[vec_off + lane + 64];
    const float g_lo = expf(gk_[vec_off + lane]);
    const float g_hi = expf(gk_[vec_off + lane + 64]);

    {   // element i -> parity i&1, chunk i>>1 ; (lane+64): same parity, chunk+32
        const int p  = lane & 1;
        const int m0 = lane >> 1;
        aL [wid][p][m0] = a_lo;        aL [wid][p][m0 + 32] = a_hi;
        qgL[wid][p][m0] = q_lo * g_lo; qgL[wid][p][m0 + 32] = q_hi * g_hi;
        gL [wid][p][m0] = g_lo;        gL [wid][p][m0 + 32] = g_hi;
        bL [wid][p][m0] = b_lo;        bL [wid][p][m0 + 32] = b_hi;
        kL [wid][p][m0] = k_lo;        kL [wid][p][m0 + 32] = k_hi;
    }

    // ---- alpha = q.b, beta = q.k : butterfly, all lanes get totals ----
    float alpha = q_lo * b_lo + q_hi * b_hi;
    float beta  = q_lo * k_lo + q_hi * k_hi;
#pragma unroll
    for (int o = 32; o > 0; o >>= 1) {
        alpha += __shfl_xor(alpha, o, 64);
        beta  += __shfl_xor(beta,  o, 64);
    }

    // v for my 4 columns
    const f32x4 v4 = *(const f32x4*)(v_ + vec_off + c4);

    // chunk m covers rows 2m (half 0) and 2m+1 (half 1); my element:
    //   h0_[h_off + (2m+half)*VD + c4]  =  hp + m*256
    const float* hp = h0_ + h_off + (size_t)half * VD + c4;

    // ---- phase 1: s/t partials over my 64 rows ----
    f32x4 sp = {0.f, 0.f, 0.f, 0.f};
    f32x4 tp = {0.f, 0.f, 0.f, 0.f};
    f32x4 Hk[RKEEP];

#pragma unroll
    for (int mb = 0; mb < NSTRM / 4; ++mb) {
        const f32x4 av = *(const f32x4*)&aL [wid][half][mb * 4];
        const f32x4 qv = *(const f32x4*)&qgL[wid][half][mb * 4];
#pragma unroll
        for (int e = 0; e < 4; ++e) {
            const int m = mb * 4 + e;
            const f32x4 h = *(const f32x4*)(hp + (size_t)m * 256);
            sp += av[e] * h;
            tp += qv[e] * h;
        }
    }
#pragma unroll
    for (int j = 0; j < RKEEP; ++j) {
        const int m = NSTRM + j;
        Hk[j] = *(const f32x4*)(hp + (size_t)m * 256);
        sp += aL [wid][half][m] * Hk[j];
        tp += qgL[wid][half][m] * Hk[j];
    }

    // ---- wave-local combine across parities (even+odd rows) ----
    f32x4 s4, t4;
#pragma unroll
    for (int e = 0; e < 4; ++e) {
        s4[e] = sp[e] + __shfl_xor(sp[e], 32, 64);
        t4[e] = tp[e] + __shfl_xor(tp[e], 32, 64);
    }

    // ---- o = t + alpha*s + beta*v (half 0 lanes: cols 0..127) ----
    if (half == 0) {
        const f32x4 o4 = t4 + alpha * s4 + beta * v4;
        *(f32x4*)(out_ + (size_t)bh * VD + c4) = o4;
    }

    // ---- phase 2: Ht = g*H + b s^T + k v^T (re-read streamed chunks) ----
    float* op = out_ + (size_t)BH_TOTAL * VD + h_off + (size_t)half * VD + c4;
#pragma unroll
    for (int mb = 0; mb < NSTRM / 4; ++mb) {
        const f32x4 gv = *(const f32x4*)&gL[wid][half][mb * 4];
        const f32x4 bv = *(const f32x4*)&bL[wid][half][mb * 4];
        const f32x4 kv = *(const f32x4*)&kL[wid][half][mb * 4];
#pragma unroll
        for (int e = 0; e < 4; ++e) {
            const int m = mb * 4 + e;
            const f32x4 h = __builtin_nontemporal_load((const f32x4*)(hp + (size_t)m * 256));
            const f32x4 o4 = gv[e] * h + bv[e] * s4 + kv[e] * v4;
            __builtin_nontemporal_store(o4, (f32x4*)(op + (size_t)m * 256));
        }
    }
#pragma unroll
    for (int j = 0; j < RKEEP; ++j) {
        const int m = NSTRM + j;
        const f32x4 o4 = gL[wid][half][m] * Hk[j] + bL[wid][half][m] * s4
                       + kL[wid][half][m] * v4;
        __builtin_nontemporal_store(o4, (f32x4*)(op + (size_t)m * 256));
    }
}

extern "C" void kernel_launch(void* const* d_in, const int* in_sizes, int n_in,
                              void* d_out, int out_size, void* d_ws, size_t ws_size,
                              hipStream_t stream) {
    const float* q  = (const float*)d_in[0];
    const float* k  = (const float*)d_in[1];
    const float* v  = (const float*)d_in[2];
    const float* a  = (const float*)d_in[3];
    const float* b  = (const float*)d_in[4];
    const float* gk = (const float*)d_in[5];
    const float* h0 = (const float*)d_in[6];
    float* out = (float*)d_out;

    dplr_decode_wave_kernel<<<NBLK, 256, 0, stream>>>(q, k, v, a, b, gk, h0, out);
}